// Round 3
// baseline (519.438 us; speedup 1.0000x reference)
//
#include <hip/hip_runtime.h>
#include <hip/hip_fp16.h>
#include <math.h>

// Problem constants: B=8, T=2048, D=1024, K_SIZE=1024, fp32 in/out.
#define B_   8
#define T_   2048
#define D_   1024
#define KSZ  1024
#define NSLOT 8             // T_/256 softmax partial slots (one per 256-row tile)
#define NTRI128 136         // 16*17/2 lower-triangle 128x128 tiles (pnorm)
#define NTRI256 36          // 8*9/2 lower-triangle 256x256 tiles (qk)

typedef _Float16 f16;
typedef _Float16 f16x8 __attribute__((ext_vector_type(8)));
typedef _Float16 f16x4 __attribute__((ext_vector_type(4)));
typedef float f32x4 __attribute__((ext_vector_type(4)));

#define GLOBAL_AS __attribute__((address_space(1)))
#define LDS_AS    __attribute__((address_space(3)))

// Async global->LDS, 16 B per lane. HW: LDS dest = wave-uniform base + lane*16.
static __device__ __forceinline__ void cp16(void* l, const void* g) {
  __builtin_amdgcn_global_load_lds((GLOBAL_AS void*)g, (LDS_AS void*)l, 16, 0, 0);
}

// Guarded online-softmax pair combine: (m1,d1) += (m2,d2)
static __device__ __forceinline__ void sm_combine(float& m1, float& d1,
                                                  float m2, float d2) {
  const float nm = fmaxf(m1, m2);
  float d = 0.f;
  if (d1 > 0.f) d += d1 * __expf(m1 - nm);
  if (d2 > 0.f) d += d2 * __expf(m2 - nm);
  m1 = nm; d1 = d;
}

// ---------------------------------------------------------------------------
// Prep: fp32 -> fp16 cast (vectorized)
// ---------------------------------------------------------------------------
__global__ __launch_bounds__(256)
void cast_f16_kernel(const float* __restrict__ X, f16* __restrict__ Xh) {
  const size_t i = ((size_t)blockIdx.x * 256 + threadIdx.x) * 4;
  float4 v = *(const float4*)&X[i];
  f16x4 o = {(f16)v.x, (f16)v.y, (f16)v.z, (f16)v.w};
  *(f16x4*)&Xh[i] = o;
}

// Prep: W[k][n] -> Wt[n][k] fp16 (1024x1024), LDS-tiled (coalesced both sides)
__global__ __launch_bounds__(256)
void transcast_kernel(const float* __restrict__ W, f16* __restrict__ Wt) {
  __shared__ float tile[32][33];          // +1 pad: conflict-free transpose
  const int c  = threadIdx.x & 31;
  const int r0 = threadIdx.x >> 5;        // 0..7
  const int n0 = blockIdx.x * 32, k0 = blockIdx.y * 32;
#pragma unroll
  for (int rr = 0; rr < 32; rr += 8)
    tile[r0 + rr][c] = W[(size_t)(k0 + r0 + rr) * 1024 + n0 + c];
  __syncthreads();
#pragma unroll
  for (int rr = 0; rr < 32; rr += 8)
    Wt[(size_t)(n0 + r0 + rr) * 1024 + k0 + c] = (f16)tile[c][r0 + rr];
}

// ===========================================================================
// 256x256 8-wave phased MFMA core (plain-HIP port of the 8-phase template).
//  - tile 256x256, BK=64, 512 threads = 8 waves (2M x 4N), per-wave 128x64
//  - LDS 128 KiB: double-buffered A[256][64] + B[256][64] f16
//  - st_16x32 swizzle: 32B-granule slot ^= (row>>2)&1, applied on the
//    pre-swizzled GLOBAL source (global_load_lds writes linearly) and on the
//    ds_read address (both-sides-or-neither).
//  - 4 phases per K-tile, counted vmcnt(4) once per tile (never 0 mid-loop),
//    raw s_barrier pairs per phase, setprio(1) around each 16-MFMA cluster.
// ===========================================================================

// Stage one 128-row half of a [256][64] K-tile panel. Per wave: 2 issues.
static __device__ __forceinline__ void stage_half(const f16* __restrict__ G,
                                                  const int ldg, f16* R,
                                                  const int half, const int kcol0,
                                                  const int wv, const int lane) {
#pragma unroll
  for (int i = 0; i < 2; ++i) {
    const int row = half * 128 + (i * 8 + wv) * 8 + (lane >> 3);
    const int slot = (lane & 7) ^ ((row & 4) >> 1);   // inverse st_16x32 swizzle
    cp16(R + half * 8192 + (i * 8 + wv) * 512,
         G + (size_t)row * ldg + kcol0 + slot * 8);
  }
}

template <int MH, int NH>
static __device__ __forceinline__ void mfma_quad(f32x4 (&acc)[8][4],
                                                 const f16x8 (&af)[4][2],
                                                 const f16x8 (&bf)[4][2]) {
#pragma unroll
  for (int m2 = 0; m2 < 4; ++m2)
#pragma unroll
    for (int n2 = 0; n2 < 2; ++n2)
#pragma unroll
      for (int ks = 0; ks < 2; ++ks)
        acc[MH * 4 + m2][NH * 2 + n2] = __builtin_amdgcn_mfma_f32_16x16x32_f16(
            af[m2][ks], bf[NH * 2 + n2][ks], acc[MH * 4 + m2][NH * 2 + n2], 0, 0, 0);
}

static __device__ __forceinline__ void kloop256(const f16* __restrict__ Ag, int lda,
                                                const f16* __restrict__ Bg, int ldb,
                                                int NT,
                                                f16 (*SA)[256 * 64], f16 (*SB)[256 * 64],
                                                f32x4 (&acc)[8][4],
                                                int wv, int lane) {
  const int wr = wv >> 2, wc = wv & 3;
  const int fr = lane & 15, quad = lane >> 4;
  const int csw = (fr & 4) << 2;               // read-side swizzle (f16 units)
  const int ck0 = (quad * 8) ^ csw;            // ks=0 column offset
  const int ck1 = ((quad + 4) * 8) ^ csw;      // ks=1 column offset
  f16x8 af[4][2], bf[4][2];

  // prologue: stage K-tile 0 (A lo/hi, B lo/hi) = 8 loads/wave
  stage_half(Ag, lda, SA[0], 0, 0, wv, lane);
  stage_half(Ag, lda, SA[0], 1, 0, wv, lane);
  stage_half(Bg, ldb, SB[0], 0, 0, wv, lane);
  stage_half(Bg, ldb, SB[0], 1, 0, wv, lane);

  int buf = 0;
  for (int t = 0; t < NT; ++t) {
    const int nbuf = buf ^ 1;
    const int kn = (t + 1) * 64;
    const bool pre = (t + 1 < NT);
    // ---- phase 0: stage A(t+1); confirm tile t; read A-lo + B[0..1]; MFMA(lo,lo)
    if (pre) {
      stage_half(Ag, lda, SA[nbuf], 0, kn, wv, lane);
      stage_half(Ag, lda, SA[nbuf], 1, kn, wv, lane);
      asm volatile("s_waitcnt vmcnt(4)" ::: "memory");  // tile t complete; A(t+1) in flight
    } else {
      asm volatile("s_waitcnt vmcnt(0)" ::: "memory");
    }
    __builtin_amdgcn_s_barrier();
    asm volatile("" ::: "memory");
    const f16* SAb = SA[buf];
    const f16* SBb = SB[buf];
#pragma unroll
    for (int m2 = 0; m2 < 4; ++m2) {
      const f16* p = SAb + (wr * 128 + m2 * 16 + fr) * 64;
      af[m2][0] = *(const f16x8*)(p + ck0);
      af[m2][1] = *(const f16x8*)(p + ck1);
    }
#pragma unroll
    for (int n2 = 0; n2 < 2; ++n2) {
      const f16* p = SBb + (wc * 64 + n2 * 16 + fr) * 64;
      bf[n2][0] = *(const f16x8*)(p + ck0);
      bf[n2][1] = *(const f16x8*)(p + ck1);
    }
    __builtin_amdgcn_s_setprio(1);
    mfma_quad<0, 0>(acc, af, bf);
    __builtin_amdgcn_s_setprio(0);
    asm volatile("" ::: "memory");
    __builtin_amdgcn_s_barrier();
    // ---- phase 1: stage B-lo(t+1); read B[2..3]; MFMA(lo,hi)
    if (pre) stage_half(Bg, ldb, SB[nbuf], 0, kn, wv, lane);
    __builtin_amdgcn_s_barrier();
    asm volatile("" ::: "memory");
#pragma unroll
    for (int n2 = 2; n2 < 4; ++n2) {
      const f16* p = SBb + (wc * 64 + n2 * 16 + fr) * 64;
      bf[n2][0] = *(const f16x8*)(p + ck0);
      bf[n2][1] = *(const f16x8*)(p + ck1);
    }
    __builtin_amdgcn_s_setprio(1);
    mfma_quad<0, 1>(acc, af, bf);
    __builtin_amdgcn_s_setprio(0);
    asm volatile("" ::: "memory");
    __builtin_amdgcn_s_barrier();
    // ---- phase 2: stage B-hi(t+1); read A-hi; MFMA(hi,lo)
    if (pre) stage_half(Bg, ldb, SB[nbuf], 1, kn, wv, lane);
    __builtin_amdgcn_s_barrier();
    asm volatile("" ::: "memory");
#pragma unroll
    for (int m2 = 0; m2 < 4; ++m2) {
      const f16* p = SAb + (wr * 128 + 64 + m2 * 16 + fr) * 64;
      af[m2][0] = *(const f16x8*)(p + ck0);
      af[m2][1] = *(const f16x8*)(p + ck1);
    }
    __builtin_amdgcn_s_setprio(1);
    mfma_quad<1, 0>(acc, af, bf);
    __builtin_amdgcn_s_setprio(0);
    asm volatile("" ::: "memory");
    __builtin_amdgcn_s_barrier();
    // ---- phase 3: MFMA(hi,hi)
    __builtin_amdgcn_s_setprio(1);
    mfma_quad<1, 1>(acc, af, bf);
    __builtin_amdgcn_s_setprio(0);
    asm volatile("" ::: "memory");
    __builtin_amdgcn_s_barrier();
    buf = nbuf;
  }
}

// ---------------------------------------------------------------------------
// Merged Q/K/V projection: C[m,n] = sum_k Xh[m,k]*Wt[n,k] + bias, N=3072.
// Wt = [Wq^T | Wk^T | Wv^T] rows. 256-col tiles never straddle a matrix
// boundary -> per-block uniform epilogue branch.
// ---------------------------------------------------------------------------
__global__ __launch_bounds__(512, 2)
void proj_qkv(const f16* __restrict__ Xh, const f16* __restrict__ Wt,
              const float* __restrict__ bq, const float* __restrict__ bk,
              const float* __restrict__ bv,
              f16* __restrict__ Qh, f16* __restrict__ Kh, f16* __restrict__ Vt) {
  const int jtn = blockIdx.x, itm = blockIdx.y;
  const int arow0 = itm * 256, col0 = jtn * 256;
  __shared__ f16 SA[2][256 * 64];
  __shared__ f16 SB[2][256 * 64];
  const int tid = threadIdx.x, lane = tid & 63, wv = tid >> 6;
  f32x4 acc[8][4] = {};
  kloop256(Xh + (size_t)arow0 * KSZ, KSZ, Wt + (size_t)col0 * KSZ, KSZ,
           KSZ / 64, SA, SB, acc, wv, lane);

  const int wr = wv >> 2, wc = wv & 3, fr = lane & 15, quad = lane >> 4;
  const int mat = jtn >> 2;                 // 0=Q, 1=K, 2=V
  const float* bp = (mat == 0) ? bq : (mat == 1) ? bk : bv;
  const int cb = col0 - mat * 1024 + wc * 64;
#pragma unroll
  for (int mi = 0; mi < 8; ++mi) {
#pragma unroll
    for (int ni = 0; ni < 4; ++ni) {
      const int cl = cb + ni * 16 + fr;
      const float bc = bp[cl];
      const int grow = arow0 + wr * 128 + mi * 16 + quad * 4;
      f32x4 v = acc[mi][ni];
      if (mat == 2) {
        const int bb = grow >> 11, t0 = grow & 2047;
        f16x4 pk;
#pragma unroll
        for (int rg = 0; rg < 4; ++rg) pk[rg] = (f16)(v[rg] + bc);
        *(f16x4*)&Vt[((size_t)bb * D_ + cl) * T_ + t0] = pk;
      } else {
        f16* O = (mat == 0) ? Qh : Kh;
#pragma unroll
        for (int rg = 0; rg < 4; ++rg)
          O[(size_t)(grow + rg) * KSZ + cl] = (f16)(v[rg] + bc);
      }
    }
  }
}

// ---------------------------------------------------------------------------
// Fused triangular QK pass (256x256 tiles): S = Q.K^T, per-tile column stats
// (m, sum-exp) -> pm/pd, and E = exp(S - m_tile_j) -> Ec (0 above diagonal).
// ---------------------------------------------------------------------------
__global__ __launch_bounds__(512, 2)
void qk_fused(const f16* __restrict__ Q, const f16* __restrict__ Km,
              float* __restrict__ pm, float* __restrict__ pd,
              f16* __restrict__ Ec) {
  const int p = blockIdx.x, b = blockIdx.y;
  int itg = (int)((sqrtf(8.f * p + 1.f) - 1.f) * 0.5f);
  while ((itg + 1) * (itg + 2) / 2 <= p) ++itg;
  while (itg * (itg + 1) / 2 > p) --itg;
  const int jt = p - itg * (itg + 1) / 2;
  const bool diag = (jt == itg);
  const int arow0 = itg * 256, col0 = jt * 256;

  __shared__ f16 SA[2][256 * 64];
  __shared__ f16 SB[2][256 * 64];
  __shared__ float red_m[8][64];
  __shared__ float red_d[8][64];
  __shared__ float mb[256];

  const int tid = threadIdx.x, lane = tid & 63, wv = tid >> 6;
  f32x4 acc[8][4] = {};
  kloop256(Q + (size_t)b * T_ * KSZ + (size_t)arow0 * KSZ, KSZ,
           Km + (size_t)b * T_ * KSZ + (size_t)col0 * KSZ, KSZ,
           KSZ / 64, SA, SB, acc, wv, lane);

  const int wr = wv >> 2, wc = wv & 3, fr = lane & 15, quad = lane >> 4;
  // per-column (m, d) over this block's 256 rows: two-pass max then exp.
#pragma unroll
  for (int ni = 0; ni < 4; ++ni) {
    const int cl = wc * 64 + ni * 16 + fr;
    const int gj = col0 + cl;
    float lm = -INFINITY;
#pragma unroll
    for (int mi = 0; mi < 8; ++mi) {
      const int gi0 = arow0 + wr * 128 + mi * 16 + quad * 4;
#pragma unroll
      for (int rg = 0; rg < 4; ++rg)
        if (!diag || (gi0 + rg >= gj)) lm = fmaxf(lm, acc[mi][ni][rg]);
    }
    float ld = 0.f;
#pragma unroll
    for (int mi = 0; mi < 8; ++mi) {
      const int gi0 = arow0 + wr * 128 + mi * 16 + quad * 4;
#pragma unroll
      for (int rg = 0; rg < 4; ++rg)
        if (!diag || (gi0 + rg >= gj)) ld += __expf(acc[mi][ni][rg] - lm);
    }
    sm_combine(lm, ld, __shfl_xor(lm, 16), __shfl_xor(ld, 16));
    sm_combine(lm, ld, __shfl_xor(lm, 32), __shfl_xor(ld, 32));
    if (quad == 0) { red_m[wv][ni * 16 + fr] = lm; red_d[wv][ni * 16 + fr] = ld; }
  }
  __syncthreads();
  if (tid < 256) {
    const int c = tid, wcc = c >> 6, cc = c & 63;
    float m1 = red_m[wcc][cc], d1 = red_d[wcc][cc];
    sm_combine(m1, d1, red_m[4 + wcc][cc], red_d[4 + wcc][cc]);
    const int idx = (itg * B_ + b) * T_ + col0 + c;
    pm[idx] = m1;
    pd[idx] = d1;
    mb[c] = m1;
  }
  __syncthreads();

  // store E = exp(S - m_tile_j) fp16 (0 above the diagonal)
  f16* Eb = Ec + (size_t)b * T_ * T_;
#pragma unroll
  for (int ni = 0; ni < 4; ++ni) {
    const int cl = wc * 64 + ni * 16 + fr;
    const int gj = col0 + cl;
    const float mj = mb[cl];
#pragma unroll
    for (int mi = 0; mi < 8; ++mi) {
      const int gi0 = arow0 + wr * 128 + mi * 16 + quad * 4;
#pragma unroll
      for (int rg = 0; rg < 4; ++rg) {
        float v = 0.f;
        if (!diag || (gi0 + rg >= gj)) v = __expf(acc[mi][ni][rg] - mj);
        Eb[(size_t)(gi0 + rg) * T_ + gj] = (f16)v;
      }
    }
  }
}

// ---------------------------------------------------------------------------
// PV + residual: out[b,t,v] = sum_j P[t,j] Vt[v,j] + X. Triangular K.
// ---------------------------------------------------------------------------
__global__ __launch_bounds__(512, 2)
void pv_gemm(const f16* __restrict__ Pm, const f16* __restrict__ Vt,
             float* __restrict__ Of, const float* __restrict__ Resid) {
  const int jt = blockIdx.x, it = blockIdx.y, b = blockIdx.z;
  const int arow0 = it * 256, col0 = jt * 256;
  __shared__ f16 SA[2][256 * 64];
  __shared__ f16 SB[2][256 * 64];
  const int tid = threadIdx.x, lane = tid & 63, wv = tid >> 6;
  f32x4 acc[8][4] = {};
  kloop256(Pm + (size_t)b * T_ * T_ + (size_t)arow0 * T_, T_,
           Vt + (size_t)b * D_ * T_ + (size_t)col0 * T_, T_,
           (it + 1) * 4, SA, SB, acc, wv, lane);

  const int wr = wv >> 2, wc = wv & 3, fr = lane & 15, quad = lane >> 4;
#pragma unroll
  for (int mi = 0; mi < 8; ++mi) {
#pragma unroll
    for (int ni = 0; ni < 4; ++ni) {
      const int col = col0 + wc * 64 + ni * 16 + fr;
      const int grow = arow0 + wr * 128 + mi * 16 + quad * 4;
      f32x4 v = acc[mi][ni];
#pragma unroll
      for (int rg = 0; rg < 4; ++rg) {
        const size_t o = ((size_t)b * T_ + grow + rg) * D_ + col;
        Of[o] = v[rg] + Resid[o];
      }
    }
  }
}

// ---------------------------------------------------------------------------
// Combine NSLOT partials per column; fold 1/sqrt(K)=1/32 into rcol.
// ---------------------------------------------------------------------------
__global__ __launch_bounds__(256)
void colstats_combine(const float* __restrict__ pm, const float* __restrict__ pd,
                      float* __restrict__ mcol, float* __restrict__ rcol) {
  const int j = blockIdx.x * 256 + threadIdx.x;
  const int b = blockIdx.y;
  float m = -INFINITY, d = 0.f;
  for (int s = 0; s < NSLOT; ++s) {
    const int idx = (s * B_ + b) * T_ + j;
    const float pmv = pm[idx], pdv = pd[idx];
    if (pdv > 0.f) sm_combine(m, d, pmv, pdv);
  }
  mcol[b * T_ + j] = m;
  rcol[b * T_ + j] = 1.f / (d * 32.f);
}

// ---------------------------------------------------------------------------
// Elementwise normalize (in place): P = E * exp(pm_tile - m_col) * r_col.
// 128x128 tiles over the lower triangle; pm slot = 256-row granule.
// ---------------------------------------------------------------------------
__global__ __launch_bounds__(256)
void pnorm_kernel(f16* __restrict__ Pc, const float* __restrict__ pm,
                  const float* __restrict__ mcol, const float* __restrict__ rcol) {
  const int p = blockIdx.x, b = blockIdx.y;
  int itg = (int)((sqrtf(8.f * p + 1.f) - 1.f) * 0.5f);
  while ((itg + 1) * (itg + 2) / 2 <= p) ++itg;
  while (itg * (itg + 1) / 2 > p) --itg;
  const int jt = p - itg * (itg + 1) / 2;

  __shared__ float f[128];
  const int tid = threadIdx.x;
  if (tid < 128) {
    const int gj = jt * 128 + tid;
    f[tid] = __expf(pm[((itg >> 1) * B_ + b) * T_ + gj] - mcol[b * T_ + gj]) * rcol[b * T_ + gj];
  }
  __syncthreads();

  f16* Pb = Pc + (size_t)b * T_ * T_ + (size_t)(itg * 128) * T_ + jt * 128;
  const int jl = (tid & 15) * 8, r0 = tid >> 4;
#pragma unroll
  for (int rr = 0; rr < 128; rr += 16) {
    f16x8 v = *(const f16x8*)&Pb[(size_t)(rr + r0) * T_ + jl];
    f16x8 o;
#pragma unroll
    for (int u = 0; u < 8; ++u) o[u] = (f16)((float)v[u] * f[jl + u]);
    *(f16x8*)&Pb[(size_t)(rr + r0) * T_ + jl] = o;
  }
}

// ---------------------------------------------------------------------------
extern "C" void kernel_launch(void* const* d_in, const int* in_sizes, int n_in,
                              void* d_out, int out_size, void* d_ws, size_t ws_size,
                              hipStream_t stream) {
  const float* X  = (const float*)d_in[0];
  const float* Wq = (const float*)d_in[1];
  const float* bq = (const float*)d_in[2];
  const float* Wk = (const float*)d_in[3];
  const float* bk = (const float*)d_in[4];
  const float* Wv = (const float*)d_in[5];
  const float* bv = (const float*)d_in[6];
  float* out = (float*)d_out;

  // Workspace carve (~200 MB)
  char* p = (char*)d_ws;
  auto carve = [&](size_t bytes) { char* r = p; p += (bytes + 255) & ~(size_t)255; return r; };
  f16*   Xh    = (f16*)carve((size_t)B_ * T_ * D_ * 2);
  f16*   Wqkvt = (f16*)carve((size_t)3 * D_ * KSZ * 2);
  f16*   Qh    = (f16*)carve((size_t)B_ * T_ * KSZ * 2);
  f16*   Kh    = (f16*)carve((size_t)B_ * T_ * KSZ * 2);
  f16*   Vt    = (f16*)carve((size_t)B_ * D_ * T_ * 2);
  f16*   Pc    = (f16*)carve((size_t)B_ * T_ * T_ * 2);   // E, then P in place
  float* pm    = (float*)carve((size_t)NSLOT * B_ * T_ * 4);
  float* pd    = (float*)carve((size_t)NSLOT * B_ * T_ * 4);
  float* mcol  = (float*)carve((size_t)B_ * T_ * 4);
  float* rcol  = (float*)carve((size_t)B_ * T_ * 4);

  const dim3 blk(256);

  // Prep: cast + weight transposes into concatenated [3072][1024] f16.
  hipMemsetAsync(pd, 0, (size_t)NSLOT * B_ * T_ * 4, stream);
  cast_f16_kernel<<<dim3((B_ * T_ * D_ / 4) / 256), blk, 0, stream>>>(X, Xh);
  transcast_kernel<<<dim3(32, 32), blk, 0, stream>>>(Wq, Wqkvt);
  transcast_kernel<<<dim3(32, 32), blk, 0, stream>>>(Wk, Wqkvt + (size_t)D_ * KSZ);
  transcast_kernel<<<dim3(32, 32), blk, 0, stream>>>(Wv, Wqkvt + (size_t)2 * D_ * KSZ);

  // Merged QKV projection (MFMA, 256^2 phased core)
  proj_qkv<<<dim3(12, 64), dim3(512), 0, stream>>>(Xh, Wqkvt, bq, bk, bv, Qh, Kh, Vt);

  // Fused QK pass: stats + E = exp(S - m_tile) into Pc
  qk_fused<<<dim3(NTRI256, B_), dim3(512), 0, stream>>>(Qh, Kh, pm, pd, Pc);
  colstats_combine<<<dim3(T_ / 256, B_), blk, 0, stream>>>(pm, pd, mcol, rcol);

  // Elementwise rescale E -> P (in place)
  pnorm_kernel<<<dim3(NTRI128, B_), blk, 0, stream>>>(Pc, pm, mcol, rcol);

  // PV + residual
  pv_gemm<<<dim3(4, 8, 8), dim3(512), 0, stream>>>(Pc, Vt, out, X);
}

// Round 6
// 507.570 us; speedup vs baseline: 1.0234x; 1.0234x over previous
//
#include <hip/hip_runtime.h>
#include <hip/hip_fp16.h>
#include <math.h>

// Problem constants: B=8, T=2048, D=1024, K_SIZE=1024, fp32 in/out.
#define B_   8
#define T_   2048
#define D_   1024
#define KSZ  1024
#define NSLOT 8             // T_/256 softmax partial slots (one per 256-row tile)
#define NTRI128 136         // 16*17/2 lower-triangle 128x128 tiles (pnorm)
#define NTRI256 36          // 8*9/2 lower-triangle 256x256 tiles (qk)

typedef _Float16 f16;
typedef _Float16 f16x8 __attribute__((ext_vector_type(8)));
typedef _Float16 f16x4 __attribute__((ext_vector_type(4)));
typedef float f32x4 __attribute__((ext_vector_type(4)));

#define GLOBAL_AS __attribute__((address_space(1)))
#define LDS_AS    __attribute__((address_space(3)))

// Async global->LDS, 16 B per lane. HW: LDS dest = wave-uniform base + lane*16.
static __device__ __forceinline__ void cp16(void* l, const void* g) {
  __builtin_amdgcn_global_load_lds((GLOBAL_AS void*)g, (LDS_AS void*)l, 16, 0, 0);
}

// Guarded online-softmax pair combine: (m1,d1) += (m2,d2)
static __device__ __forceinline__ void sm_combine(float& m1, float& d1,
                                                  float m2, float d2) {
  const float nm = fmaxf(m1, m2);
  float d = 0.f;
  if (d1 > 0.f) d += d1 * __expf(m1 - nm);
  if (d2 > 0.f) d += d2 * __expf(m2 - nm);
  m1 = nm; d1 = d;
}

// ---------------------------------------------------------------------------
// Prep: fp32 -> fp16 cast (vectorized)
// ---------------------------------------------------------------------------
__global__ __launch_bounds__(256)
void cast_f16_kernel(const float* __restrict__ X, f16* __restrict__ Xh) {
  const size_t i = ((size_t)blockIdx.x * 256 + threadIdx.x) * 4;
  float4 v = *(const float4*)&X[i];
  f16x4 o = {(f16)v.x, (f16)v.y, (f16)v.z, (f16)v.w};
  *(f16x4*)&Xh[i] = o;
}

// Prep: W[k][n] -> Wt[n][k] fp16 (1024x1024), LDS-tiled (coalesced both sides)
__global__ __launch_bounds__(256)
void transcast_kernel(const float* __restrict__ W, f16* __restrict__ Wt) {
  __shared__ float tile[32][33];          // +1 pad: conflict-free transpose
  const int c  = threadIdx.x & 31;
  const int r0 = threadIdx.x >> 5;        // 0..7
  const int n0 = blockIdx.x * 32, k0 = blockIdx.y * 32;
#pragma unroll
  for (int rr = 0; rr < 32; rr += 8)
    tile[r0 + rr][c] = W[(size_t)(k0 + r0 + rr) * 1024 + n0 + c];
  __syncthreads();
#pragma unroll
  for (int rr = 0; rr < 32; rr += 8)
    Wt[(size_t)(n0 + r0 + rr) * 1024 + k0 + c] = (f16)tile[c][r0 + rr];
}

// ===========================================================================
// 256x256 8-wave phased MFMA core. Panels are [rows][64] f16 (128 B rows).
// XOR-8 swizzle (G4's measured fix for 128B-row column reads):
//   LDS(row, chunk16B) holds global(row, chunk ^ (row&7)); reads use
//   chunk' = chunk ^ (row&7). Spreads the 8 16B-slots of each row across
//   all 32 banks (residual 2-way = free). Write side is the pre-swizzled
//   GLOBAL source (global_load_lds writes linearly; rule #21).
// ===========================================================================

// Stage one 128-row half of a [*][64] K-tile panel. Per wave: 2 cp16.
// Lane l covers row (..)+ (l>>3), chunk l&7; row&7 == l>>3.
static __device__ __forceinline__ void stage_half(const f16* __restrict__ G,
                                                  const int ldg, f16* R,
                                                  const int half, const int kcol0,
                                                  const int wv, const int lane) {
#pragma unroll
  for (int i = 0; i < 2; ++i) {
    const int row  = half * 128 + (i * 8 + wv) * 8 + (lane >> 3);
    const int slot = (lane & 7) ^ (lane >> 3);       // inverse XOR-8 swizzle
    cp16(R + half * 8192 + (i * 8 + wv) * 512,
         G + (size_t)row * ldg + kcol0 + slot * 8);
  }
}

template <int MH, int NH>
static __device__ __forceinline__ void mfma_quad(f32x4 (&acc)[8][4],
                                                 const f16x8 (&af)[4][2],
                                                 const f16x8 (&bf)[4][2]) {
#pragma unroll
  for (int m2 = 0; m2 < 4; ++m2)
#pragma unroll
    for (int n2 = 0; n2 < 2; ++n2)
#pragma unroll
      for (int ks = 0; ks < 2; ++ks)
        acc[MH * 4 + m2][NH * 2 + n2] = __builtin_amdgcn_mfma_f32_16x16x32_f16(
            af[m2][ks], bf[NH * 2 + n2][ks], acc[MH * 4 + m2][NH * 2 + n2], 0, 0, 0);
}

// 256x256 tile, 8 waves (2M x 4N), BK=64, double-buffered, 4 phases/K-tile,
// counted vmcnt(4) once per tile (never 0 mid-loop), setprio around MFMA.
static __device__ __forceinline__ void kloop256(const f16* __restrict__ Ag, int lda,
                                                const f16* __restrict__ Bg, int ldb,
                                                int NT,
                                                f16 (*SA)[256 * 64], f16 (*SB)[256 * 64],
                                                f32x4 (&acc)[8][4],
                                                int wv, int lane) {
  const int wr = wv >> 2, wc = wv & 3;
  const int fr = lane & 15, quad = lane >> 4;
  const int s8 = fr & 7;                       // = row&7 for every fragment row
  const int ck0 = (quad ^ s8) * 8;             // ks=0 chunk (f16 units)
  const int ck1 = ((quad + 4) ^ s8) * 8;       // ks=1 chunk
  f16x8 af[4][2], bf[4][2];

  // prologue: stage K-tile 0 (A lo/hi, B lo/hi) = 8 loads/wave
  stage_half(Ag, lda, SA[0], 0, 0, wv, lane);
  stage_half(Ag, lda, SA[0], 1, 0, wv, lane);
  stage_half(Bg, ldb, SB[0], 0, 0, wv, lane);
  stage_half(Bg, ldb, SB[0], 1, 0, wv, lane);

  int buf = 0;
  for (int t = 0; t < NT; ++t) {
    const int nbuf = buf ^ 1;
    const int kn = (t + 1) * 64;
    const bool pre = (t + 1 < NT);
    // ---- phase 0: stage A(t+1); confirm tile t; read A-lo + B[0..1]; MFMA(lo,lo)
    if (pre) {
      stage_half(Ag, lda, SA[nbuf], 0, kn, wv, lane);
      stage_half(Ag, lda, SA[nbuf], 1, kn, wv, lane);
      asm volatile("s_waitcnt vmcnt(4)" ::: "memory");  // tile t complete; A(t+1) in flight
    } else {
      asm volatile("s_waitcnt vmcnt(0)" ::: "memory");
    }
    __builtin_amdgcn_s_barrier();
    asm volatile("" ::: "memory");
    const f16* SAb = SA[buf];
    const f16* SBb = SB[buf];
#pragma unroll
    for (int m2 = 0; m2 < 4; ++m2) {
      const f16* p = SAb + (wr * 128 + m2 * 16 + fr) * 64;
      af[m2][0] = *(const f16x8*)(p + ck0);
      af[m2][1] = *(const f16x8*)(p + ck1);
    }
#pragma unroll
    for (int n2 = 0; n2 < 2; ++n2) {
      const f16* p = SBb + (wc * 64 + n2 * 16 + fr) * 64;
      bf[n2][0] = *(const f16x8*)(p + ck0);
      bf[n2][1] = *(const f16x8*)(p + ck1);
    }
    __builtin_amdgcn_s_setprio(1);
    mfma_quad<0, 0>(acc, af, bf);
    __builtin_amdgcn_s_setprio(0);
    asm volatile("" ::: "memory");
    __builtin_amdgcn_s_barrier();
    // ---- phase 1: stage B-lo(t+1); read B[2..3]; MFMA(lo,hi)
    if (pre) stage_half(Bg, ldb, SB[nbuf], 0, kn, wv, lane);
    __builtin_amdgcn_s_barrier();
    asm volatile("" ::: "memory");
#pragma unroll
    for (int n2 = 2; n2 < 4; ++n2) {
      const f16* p = SBb + (wc * 64 + n2 * 16 + fr) * 64;
      bf[n2][0] = *(const f16x8*)(p + ck0);
      bf[n2][1] = *(const f16x8*)(p + ck1);
    }
    __builtin_amdgcn_s_setprio(1);
    mfma_quad<0, 1>(acc, af, bf);
    __builtin_amdgcn_s_setprio(0);
    asm volatile("" ::: "memory");
    __builtin_amdgcn_s_barrier();
    // ---- phase 2: stage B-hi(t+1); read A-hi; MFMA(hi,lo)
    if (pre) stage_half(Bg, ldb, SB[nbuf], 1, kn, wv, lane);
    __builtin_amdgcn_s_barrier();
    asm volatile("" ::: "memory");
#pragma unroll
    for (int m2 = 0; m2 < 4; ++m2) {
      const f16* p = SAb + (wr * 128 + 64 + m2 * 16 + fr) * 64;
      af[m2][0] = *(const f16x8*)(p + ck0);
      af[m2][1] = *(const f16x8*)(p + ck1);
    }
    __builtin_amdgcn_s_setprio(1);
    mfma_quad<1, 0>(acc, af, bf);
    __builtin_amdgcn_s_setprio(0);
    asm volatile("" ::: "memory");
    __builtin_amdgcn_s_barrier();
    // ---- phase 3: MFMA(hi,hi)
    __builtin_amdgcn_s_setprio(1);
    mfma_quad<1, 1>(acc, af, bf);
    __builtin_amdgcn_s_setprio(0);
    asm volatile("" ::: "memory");
    __builtin_amdgcn_s_barrier();
    buf = nbuf;
  }
}

// ---------------------------------------------------------------------------
// Merged Q/K/V projection: C[m,n] = sum_k Xh[m,k]*Wt[n,k] + bias, N=3072.
// ---------------------------------------------------------------------------
__global__ __launch_bounds__(512, 2)
void proj_qkv(const f16* __restrict__ Xh, const f16* __restrict__ Wt,
              const float* __restrict__ bq, const float* __restrict__ bk,
              const float* __restrict__ bv,
              f16* __restrict__ Qh, f16* __restrict__ Kh, f16* __restrict__ Vt) {
  const int jtn = blockIdx.x, itm = blockIdx.y;
  const int arow0 = itm * 256, col0 = jtn * 256;
  __shared__ f16 SA[2][256 * 64];
  __shared__ f16 SB[2][256 * 64];
  const int tid = threadIdx.x, lane = tid & 63, wv = tid >> 6;
  f32x4 acc[8][4] = {};
  kloop256(Xh + (size_t)arow0 * KSZ, KSZ, Wt + (size_t)col0 * KSZ, KSZ,
           KSZ / 64, SA, SB, acc, wv, lane);

  const int wr = wv >> 2, wc = wv & 3, fr = lane & 15, quad = lane >> 4;
  const int mat = jtn >> 2;                 // 0=Q, 1=K, 2=V
  const float* bp = (mat == 0) ? bq : (mat == 1) ? bk : bv;
  const int cb = col0 - mat * 1024 + wc * 64;
#pragma unroll
  for (int mi = 0; mi < 8; ++mi) {
#pragma unroll
    for (int ni = 0; ni < 4; ++ni) {
      const int cl = cb + ni * 16 + fr;
      const float bc = bp[cl];
      const int grow = arow0 + wr * 128 + mi * 16 + quad * 4;
      f32x4 v = acc[mi][ni];
      if (mat == 2) {
        const int bb = grow >> 11, t0 = grow & 2047;
        f16x4 pk;
#pragma unroll
        for (int rg = 0; rg < 4; ++rg) pk[rg] = (f16)(v[rg] + bc);
        *(f16x4*)&Vt[((size_t)bb * D_ + cl) * T_ + t0] = pk;
      } else {
        f16* O = (mat == 0) ? Qh : Kh;
#pragma unroll
        for (int rg = 0; rg < 4; ++rg)
          O[(size_t)(grow + rg) * KSZ + cl] = (f16)(v[rg] + bc);
      }
    }
  }
}

// ---------------------------------------------------------------------------
// Fused triangular QK pass (256x256 tiles): S = Q.K^T, per-tile column stats
// (m, sum-exp) -> pm/pd, and E = exp(S - m_tile_j) -> Ec (0 above diagonal).
// ---------------------------------------------------------------------------
__global__ __launch_bounds__(512, 2)
void qk_fused(const f16* __restrict__ Q, const f16* __restrict__ Km,
              float* __restrict__ pm, float* __restrict__ pd,
              f16* __restrict__ Ec) {
  const int p = blockIdx.x, b = blockIdx.y;
  int itg = (int)((sqrtf(8.f * p + 1.f) - 1.f) * 0.5f);
  while ((itg + 1) * (itg + 2) / 2 <= p) ++itg;
  while (itg * (itg + 1) / 2 > p) --itg;
  const int jt = p - itg * (itg + 1) / 2;
  const bool diag = (jt == itg);
  const int arow0 = itg * 256, col0 = jt * 256;

  __shared__ f16 SA[2][256 * 64];
  __shared__ f16 SB[2][256 * 64];
  __shared__ float red_m[8][64];
  __shared__ float red_d[8][64];
  __shared__ float mb[256];

  const int tid = threadIdx.x, lane = tid & 63, wv = tid >> 6;
  f32x4 acc[8][4] = {};
  kloop256(Q + (size_t)b * T_ * KSZ + (size_t)arow0 * KSZ, KSZ,
           Km + (size_t)b * T_ * KSZ + (size_t)col0 * KSZ, KSZ,
           KSZ / 64, SA, SB, acc, wv, lane);

  const int wr = wv >> 2, wc = wv & 3, fr = lane & 15, quad = lane >> 4;
  // per-column (m, d) over this block's 256 rows: two-pass max then exp.
#pragma unroll
  for (int ni = 0; ni < 4; ++ni) {
    const int cl = wc * 64 + ni * 16 + fr;
    const int gj = col0 + cl;
    float lm = -INFINITY;
#pragma unroll
    for (int mi = 0; mi < 8; ++mi) {
      const int gi0 = arow0 + wr * 128 + mi * 16 + quad * 4;
#pragma unroll
      for (int rg = 0; rg < 4; ++rg)
        if (!diag || (gi0 + rg >= gj)) lm = fmaxf(lm, acc[mi][ni][rg]);
    }
    float ld = 0.f;
#pragma unroll
    for (int mi = 0; mi < 8; ++mi) {
      const int gi0 = arow0 + wr * 128 + mi * 16 + quad * 4;
#pragma unroll
      for (int rg = 0; rg < 4; ++rg)
        if (!diag || (gi0 + rg >= gj)) ld += __expf(acc[mi][ni][rg] - lm);
    }
    sm_combine(lm, ld, __shfl_xor(lm, 16), __shfl_xor(ld, 16));
    sm_combine(lm, ld, __shfl_xor(lm, 32), __shfl_xor(ld, 32));
    if (quad == 0) { red_m[wv][ni * 16 + fr] = lm; red_d[wv][ni * 16 + fr] = ld; }
  }
  __syncthreads();
  if (tid < 256) {
    const int c = tid, wcc = c >> 6, cc = c & 63;
    float m1 = red_m[wcc][cc], d1 = red_d[wcc][cc];
    sm_combine(m1, d1, red_m[4 + wcc][cc], red_d[4 + wcc][cc]);
    const int idx = (itg * B_ + b) * T_ + col0 + c;
    pm[idx] = m1;
    pd[idx] = d1;
    mb[c] = m1;
  }
  __syncthreads();

  // store E = exp(S - m_tile_j) fp16 (0 above the diagonal)
  f16* Eb = Ec + (size_t)b * T_ * T_;
#pragma unroll
  for (int ni = 0; ni < 4; ++ni) {
    const int cl = wc * 64 + ni * 16 + fr;
    const int gj = col0 + cl;
    const float mj = mb[cl];
#pragma unroll
    for (int mi = 0; mi < 8; ++mi) {
      const int gi0 = arow0 + wr * 128 + mi * 16 + quad * 4;
#pragma unroll
      for (int rg = 0; rg < 4; ++rg) {
        float v = 0.f;
        if (!diag || (gi0 + rg >= gj)) v = __expf(acc[mi][ni][rg] - mj);
        Eb[(size_t)(gi0 + rg) * T_ + gj] = (f16)v;
      }
    }
  }
}

// ---------------------------------------------------------------------------
// PV + residual: out[b,t,v] = sum_j P[t,j] Vt[v,j] + X. Triangular K.
// (Round-3 verified structure; K-imbalance accepted this round.)
// ---------------------------------------------------------------------------
__global__ __launch_bounds__(512, 2)
void pv_gemm(const f16* __restrict__ Pm, const f16* __restrict__ Vt,
             float* __restrict__ Of, const float* __restrict__ Resid) {
  const int jt = blockIdx.x, it = blockIdx.y, b = blockIdx.z;
  const int arow0 = it * 256, col0 = jt * 256;
  __shared__ f16 SA[2][256 * 64];
  __shared__ f16 SB[2][256 * 64];
  const int tid = threadIdx.x, lane = tid & 63, wv = tid >> 6;
  f32x4 acc[8][4] = {};
  kloop256(Pm + (size_t)b * T_ * T_ + (size_t)arow0 * T_, T_,
           Vt + (size_t)b * D_ * T_ + (size_t)col0 * T_, T_,
           (it + 1) * 4, SA, SB, acc, wv, lane);

  const int wr = wv >> 2, wc = wv & 3, fr = lane & 15, quad = lane >> 4;
#pragma unroll
  for (int mi = 0; mi < 8; ++mi) {
#pragma unroll
    for (int ni = 0; ni < 4; ++ni) {
      const int col = col0 + wc * 64 + ni * 16 + fr;
      const int grow = arow0 + wr * 128 + mi * 16 + quad * 4;
      f32x4 v = acc[mi][ni];
#pragma unroll
      for (int rg = 0; rg < 4; ++rg) {
        const size_t o = ((size_t)b * T_ + grow + rg) * D_ + col;
        Of[o] = v[rg] + Resid[o];
      }
    }
  }
}

// ---------------------------------------------------------------------------
// Combine NSLOT partials per column; fold 1/sqrt(K)=1/32 into rcol.
// ---------------------------------------------------------------------------
__global__ __launch_bounds__(256)
void colstats_combine(const float* __restrict__ pm, const float* __restrict__ pd,
                      float* __restrict__ mcol, float* __restrict__ rcol) {
  const int j = blockIdx.x * 256 + threadIdx.x;
  const int b = blockIdx.y;
  float m = -INFINITY, d = 0.f;
  for (int s = 0; s < NSLOT; ++s) {
    const int idx = (s * B_ + b) * T_ + j;
    const float pmv = pm[idx], pdv = pd[idx];
    if (pdv > 0.f) sm_combine(m, d, pmv, pdv);
  }
  mcol[b * T_ + j] = m;
  rcol[b * T_ + j] = 1.f / (d * 32.f);
}

// ---------------------------------------------------------------------------
// Elementwise normalize (in place): P = E * exp(pm_tile - m_col) * r_col.
// 128x128 tiles over the lower triangle; pm slot = 256-row granule.
// ---------------------------------------------------------------------------
__global__ __launch_bounds__(256)
void pnorm_kernel(f16* __restrict__ Pc, const float* __restrict__ pm,
                  const float* __restrict__ mcol, const float* __restrict__ rcol) {
  const int p = blockIdx.x, b = blockIdx.y;
  int itg = (int)((sqrtf(8.f * p + 1.f) - 1.f) * 0.5f);
  while ((itg + 1) * (itg + 2) / 2 <= p) ++itg;
  while (itg * (itg + 1) / 2 > p) --itg;
  const int jt = p - itg * (itg + 1) / 2;

  __shared__ float f[128];
  const int tid = threadIdx.x;
  if (tid < 128) {
    const int gj = jt * 128 + tid;
    f[tid] = __expf(pm[((itg >> 1) * B_ + b) * T_ + gj] - mcol[b * T_ + gj]) * rcol[b * T_ + gj];
  }
  __syncthreads();

  f16* Pb = Pc + (size_t)b * T_ * T_ + (size_t)(itg * 128) * T_ + jt * 128;
  const int jl = (tid & 15) * 8, r0 = tid >> 4;
#pragma unroll
  for (int rr = 0; rr < 128; rr += 16) {
    f16x8 v = *(const f16x8*)&Pb[(size_t)(rr + r0) * T_ + jl];
    f16x8 o;
#pragma unroll
    for (int u = 0; u < 8; ++u) o[u] = (f16)((float)v[u] * f[jl + u]);
    *(f16x8*)&Pb[(size_t)(rr + r0) * T_ + jl] = o;
  }
}

// ---------------------------------------------------------------------------
extern "C" void kernel_launch(void* const* d_in, const int* in_sizes, int n_in,
                              void* d_out, int out_size, void* d_ws, size_t ws_size,
                              hipStream_t stream) {
  const float* X  = (const float*)d_in[0];
  const float* Wq = (const float*)d_in[1];
  const float* bq = (const float*)d_in[2];
  const float* Wk = (const float*)d_in[3];
  const float* bk = (const float*)d_in[4];
  const float* Wv = (const float*)d_in[5];
  const float* bv = (const float*)d_in[6];
  float* out = (float*)d_out;

  // Workspace carve (~200 MB)
  char* p = (char*)d_ws;
  auto carve = [&](size_t bytes) { char* r = p; p += (bytes + 255) & ~(size_t)255; return r; };
  f16*   Xh    = (f16*)carve((size_t)B_ * T_ * D_ * 2);
  f16*   Wqkvt = (f16*)carve((size_t)3 * D_ * KSZ * 2);
  f16*   Qh    = (f16*)carve((size_t)B_ * T_ * KSZ * 2);
  f16*   Kh    = (f16*)carve((size_t)B_ * T_ * KSZ * 2);
  f16*   Vt    = (f16*)carve((size_t)B_ * D_ * T_ * 2);
  f16*   Pc    = (f16*)carve((size_t)B_ * T_ * T_ * 2);   // E, then P in place
  float* pm    = (float*)carve((size_t)NSLOT * B_ * T_ * 4);
  float* pd    = (float*)carve((size_t)NSLOT * B_ * T_ * 4);
  float* mcol  = (float*)carve((size_t)B_ * T_ * 4);
  float* rcol  = (float*)carve((size_t)B_ * T_ * 4);

  const dim3 blk(256);

  // Prep: cast + weight transposes into concatenated [3072][1024] f16.
  hipMemsetAsync(pd, 0, (size_t)NSLOT * B_ * T_ * 4, stream);
  cast_f16_kernel<<<dim3((B_ * T_ * D_ / 4) / 256), blk, 0, stream>>>(X, Xh);
  transcast_kernel<<<dim3(32, 32), blk, 0, stream>>>(Wq, Wqkvt);
  transcast_kernel<<<dim3(32, 32), blk, 0, stream>>>(Wk, Wqkvt + (size_t)D_ * KSZ);
  transcast_kernel<<<dim3(32, 32), blk, 0, stream>>>(Wv, Wqkvt + (size_t)2 * D_ * KSZ);

  // Merged QKV projection (MFMA, 256^2 phased core)
  proj_qkv<<<dim3(12, 64), dim3(512), 0, stream>>>(Xh, Wqkvt, bq, bk, bv, Qh, Kh, Vt);

  // Fused QK pass: stats + E = exp(S - m_tile) into Pc
  qk_fused<<<dim3(NTRI256, B_), dim3(512), 0, stream>>>(Qh, Kh, pm, pd, Pc);
  colstats_combine<<<dim3(T_ / 256, B_), blk, 0, stream>>>(pm, pd, mcol, rcol);

  // Elementwise rescale E -> P (in place)
  pnorm_kernel<<<dim3(NTRI128, B_), blk, 0, stream>>>(Pc, pm, mcol, rcol);

  // PV + residual
  pv_gemm<<<dim3(4, 8, 8), dim3(512), 0, stream>>>(Pc, Vt, out, X);
}

// Round 7
// 437.793 us; speedup vs baseline: 1.1865x; 1.1594x over previous
//
#include <hip/hip_runtime.h>
#include <hip/hip_fp16.h>
#include <math.h>

// Problem constants: B=8, T=2048, D=1024, K_SIZE=1024, fp32 in/out.
#define B_   8
#define T_   2048
#define D_   1024
#define KSZ  1024
#define NSLOT 8             // T_/256 softmax partial slots (one per 256-row tile)
#define NTRI128 136         // 16*17/2 lower-triangle 128x128 tiles (pnorm)
#define NTRI256 36          // 8*9/2 lower-triangle 256x256 tiles (qk)

typedef _Float16 f16;
typedef _Float16 f16x8 __attribute__((ext_vector_type(8)));
typedef _Float16 f16x4 __attribute__((ext_vector_type(4)));
typedef float f32x4 __attribute__((ext_vector_type(4)));

#define GLOBAL_AS __attribute__((address_space(1)))
#define LDS_AS    __attribute__((address_space(3)))

// Async global->LDS, 16 B per lane. HW: LDS dest = wave-uniform base + lane*16.
static __device__ __forceinline__ void cp16(void* l, const void* g) {
  __builtin_amdgcn_global_load_lds((GLOBAL_AS void*)g, (LDS_AS void*)l, 16, 0, 0);
}

// Guarded online-softmax pair combine: (m1,d1) += (m2,d2)
static __device__ __forceinline__ void sm_combine(float& m1, float& d1,
                                                  float m2, float d2) {
  const float nm = fmaxf(m1, m2);
  float d = 0.f;
  if (d1 > 0.f) d += d1 * __expf(m1 - nm);
  if (d2 > 0.f) d += d2 * __expf(m2 - nm);
  m1 = nm; d1 = d;
}

// ---------------------------------------------------------------------------
// Prep: fp32 -> fp16 cast (vectorized)
// ---------------------------------------------------------------------------
__global__ __launch_bounds__(256)
void cast_f16_kernel(const float* __restrict__ X, f16* __restrict__ Xh) {
  const size_t i = ((size_t)blockIdx.x * 256 + threadIdx.x) * 4;
  float4 v = *(const float4*)&X[i];
  f16x4 o = {(f16)v.x, (f16)v.y, (f16)v.z, (f16)v.w};
  *(f16x4*)&Xh[i] = o;
}

// Prep: W[k][n] -> Wt[n][k] fp16 (1024x1024), LDS-tiled (coalesced both sides)
__global__ __launch_bounds__(256)
void transcast_kernel(const float* __restrict__ W, f16* __restrict__ Wt) {
  __shared__ float tile[32][33];          // +1 pad: conflict-free transpose
  const int c  = threadIdx.x & 31;
  const int r0 = threadIdx.x >> 5;        // 0..7
  const int n0 = blockIdx.x * 32, k0 = blockIdx.y * 32;
#pragma unroll
  for (int rr = 0; rr < 32; rr += 8)
    tile[r0 + rr][c] = W[(size_t)(k0 + r0 + rr) * 1024 + n0 + c];
  __syncthreads();
#pragma unroll
  for (int rr = 0; rr < 32; rr += 8)
    Wt[(size_t)(n0 + r0 + rr) * 1024 + k0 + c] = (f16)tile[c][r0 + rr];
}

// ===========================================================================
// MFMA cores. Panels are [rows][64] f16 (128 B rows).
// XOR-8 swizzle (verified r6: SQ_LDS_BANK_CONFLICT 9.4M -> 0):
//   LDS(row, chunk16B) holds global(row, chunk ^ (row&7)); reads use
//   chunk' = chunk ^ (row&7). Write side via pre-swizzled GLOBAL source.
//
// K-loop (r7): 2 barriers/tile, counted vmcnt, full-tile-ahead prefetch.
//   stage ALL of tile t+1 -> vmcnt(N) retiring exactly tile t (t+1 stays in
//   flight ACROSS the barrier) -> acquire barrier -> read+MFMA clusters with
//   no mid-tile barriers (reads from stable buf; compiler pipelines under
//   MFMA) -> release barrier (all reads drained before MFMA consumed them,
//   so buf may be overwritten next iteration).
// ===========================================================================

// Stage one 128-row half of a [*][64] K-tile panel. Per wave: 2 cp16.
// Lane l covers row (..)+(l>>3), chunk l&7; row&7 == l>>3.
static __device__ __forceinline__ void stage_half(const f16* __restrict__ G,
                                                  const int ldg, f16* R,
                                                  const int half, const int kcol0,
                                                  const int wv, const int lane) {
#pragma unroll
  for (int i = 0; i < 2; ++i) {
    const int row  = half * 128 + (i * 8 + wv) * 8 + (lane >> 3);
    const int slot = (lane & 7) ^ (lane >> 3);       // inverse XOR-8 swizzle
    cp16(R + half * 8192 + (i * 8 + wv) * 512,
         G + (size_t)row * ldg + kcol0 + slot * 8);
  }
}

template <int MH, int NH>
static __device__ __forceinline__ void mfma_quad(f32x4 (&acc)[8][4],
                                                 const f16x8 (&af)[4][2],
                                                 const f16x8 (&bf)[4][2]) {
#pragma unroll
  for (int m2 = 0; m2 < 4; ++m2)
#pragma unroll
    for (int n2 = 0; n2 < 2; ++n2)
#pragma unroll
      for (int ks = 0; ks < 2; ++ks)
        acc[MH * 4 + m2][NH * 2 + n2] = __builtin_amdgcn_mfma_f32_16x16x32_f16(
            af[m2][ks], bf[NH * 2 + n2][ks], acc[MH * 4 + m2][NH * 2 + n2], 0, 0, 0);
}

// 256x256 tile, 8 waves (2M x 4N), BK=64, double-buffered (128 KiB).
// Steady-state wait: vmcnt(8) = tile t complete, tile t+1's 8 in flight.
static __device__ __forceinline__ void kloop256(const f16* __restrict__ Ag, int lda,
                                                const f16* __restrict__ Bg, int ldb,
                                                int NT,
                                                f16 (*SA)[256 * 64], f16 (*SB)[256 * 64],
                                                f32x4 (&acc)[8][4],
                                                int wv, int lane) {
  const int wr = wv >> 2, wc = wv & 3;
  const int fr = lane & 15, quad = lane >> 4;
  const int s8 = fr & 7;                       // = row&7 for every fragment row
  const int ck0 = (quad ^ s8) * 8;             // ks=0 chunk (f16 units)
  const int ck1 = ((quad + 4) ^ s8) * 8;       // ks=1 chunk
  f16x8 af[4][2], bf[4][2];

  // prologue: stage K-tile 0 = 8 loads/wave
  stage_half(Ag, lda, SA[0], 0, 0, wv, lane);
  stage_half(Ag, lda, SA[0], 1, 0, wv, lane);
  stage_half(Bg, ldb, SB[0], 0, 0, wv, lane);
  stage_half(Bg, ldb, SB[0], 1, 0, wv, lane);

  int buf = 0;
  for (int t = 0; t < NT; ++t) {
    const int nbuf = buf ^ 1;
    if (t + 1 < NT) {
      const int kn = (t + 1) * 64;
      stage_half(Ag, lda, SA[nbuf], 0, kn, wv, lane);
      stage_half(Ag, lda, SA[nbuf], 1, kn, wv, lane);
      stage_half(Bg, ldb, SB[nbuf], 0, kn, wv, lane);
      stage_half(Bg, ldb, SB[nbuf], 1, kn, wv, lane);
      asm volatile("s_waitcnt vmcnt(8)" ::: "memory");  // tile t done; t+1 in flight
    } else {
      asm volatile("s_waitcnt vmcnt(0)" ::: "memory");
    }
    __builtin_amdgcn_s_barrier();                        // acquire: tile t visible
    asm volatile("" ::: "memory");
    const f16* SAb = SA[buf];
    const f16* SBb = SB[buf];
    // ---- M-half 0
#pragma unroll
    for (int m2 = 0; m2 < 4; ++m2) {
      const f16* p = SAb + (wr * 128 + m2 * 16 + fr) * 64;
      af[m2][0] = *(const f16x8*)(p + ck0);
      af[m2][1] = *(const f16x8*)(p + ck1);
    }
#pragma unroll
    for (int n2 = 0; n2 < 2; ++n2) {
      const f16* p = SBb + (wc * 64 + n2 * 16 + fr) * 64;
      bf[n2][0] = *(const f16x8*)(p + ck0);
      bf[n2][1] = *(const f16x8*)(p + ck1);
    }
    __builtin_amdgcn_s_setprio(1);
    mfma_quad<0, 0>(acc, af, bf);
    __builtin_amdgcn_s_setprio(0);
#pragma unroll
    for (int n2 = 2; n2 < 4; ++n2) {
      const f16* p = SBb + (wc * 64 + n2 * 16 + fr) * 64;
      bf[n2][0] = *(const f16x8*)(p + ck0);
      bf[n2][1] = *(const f16x8*)(p + ck1);
    }
    __builtin_amdgcn_s_setprio(1);
    mfma_quad<0, 1>(acc, af, bf);
    __builtin_amdgcn_s_setprio(0);
    // ---- M-half 1 (reuse bf[0..3])
#pragma unroll
    for (int m2 = 0; m2 < 4; ++m2) {
      const f16* p = SAb + (wr * 128 + 64 + m2 * 16 + fr) * 64;
      af[m2][0] = *(const f16x8*)(p + ck0);
      af[m2][1] = *(const f16x8*)(p + ck1);
    }
    __builtin_amdgcn_s_setprio(1);
    mfma_quad<1, 0>(acc, af, bf);
    mfma_quad<1, 1>(acc, af, bf);
    __builtin_amdgcn_s_setprio(0);
    asm volatile("" ::: "memory");
    __builtin_amdgcn_s_barrier();                        // release: buf reusable
    asm volatile("" ::: "memory");
    buf = nbuf;
  }
}

// 256(M) x 128(N) tile, 8 waves (4M x 2N), BK=64, double-buffered (96 KiB).
// 6 loads/wave/tile; steady-state wait vmcnt(6). Same 2-barrier schedule.
static __device__ __forceinline__ void kloop_pv(const f16* __restrict__ Ag, int lda,
                                                const f16* __restrict__ Bg, int ldb,
                                                int NT,
                                                f16 (*SA)[256 * 64], f16 (*SB)[128 * 64],
                                                f32x4 (&acc)[4][4],
                                                int wv, int lane) {
  const int wr = wv >> 1, wc = wv & 1;
  const int fr = lane & 15, quad = lane >> 4;
  const int s8 = fr & 7;
  const int ck0 = (quad ^ s8) * 8;
  const int ck1 = ((quad + 4) ^ s8) * 8;
  f16x8 af[4][2], bf[4][2];

  // prologue: stage K-tile 0 (A lo/hi, B) = 6 loads/wave
  stage_half(Ag, lda, SA[0], 0, 0, wv, lane);
  stage_half(Ag, lda, SA[0], 1, 0, wv, lane);
  stage_half(Bg, ldb, SB[0], 0, 0, wv, lane);

  int buf = 0;
  for (int t = 0; t < NT; ++t) {
    const int nbuf = buf ^ 1;
    if (t + 1 < NT) {
      const int kn = (t + 1) * 64;
      stage_half(Ag, lda, SA[nbuf], 0, kn, wv, lane);
      stage_half(Ag, lda, SA[nbuf], 1, kn, wv, lane);
      stage_half(Bg, ldb, SB[nbuf], 0, kn, wv, lane);
      asm volatile("s_waitcnt vmcnt(6)" ::: "memory");  // tile t done; t+1 in flight
    } else {
      asm volatile("s_waitcnt vmcnt(0)" ::: "memory");
    }
    __builtin_amdgcn_s_barrier();
    asm volatile("" ::: "memory");
    const f16* SAb = SA[buf];
    const f16* SBb = SB[buf];
#pragma unroll
    for (int m2 = 0; m2 < 4; ++m2) {
      const f16* p = SAb + (wr * 64 + m2 * 16 + fr) * 64;
      af[m2][0] = *(const f16x8*)(p + ck0);
      af[m2][1] = *(const f16x8*)(p + ck1);
    }
#pragma unroll
    for (int n2 = 0; n2 < 4; ++n2) {
      const f16* p = SBb + (wc * 64 + n2 * 16 + fr) * 64;
      bf[n2][0] = *(const f16x8*)(p + ck0);
      bf[n2][1] = *(const f16x8*)(p + ck1);
    }
    __builtin_amdgcn_s_setprio(1);
#pragma unroll
    for (int m2 = 0; m2 < 4; ++m2)
#pragma unroll
      for (int n2 = 0; n2 < 4; ++n2) {
        acc[m2][n2] = __builtin_amdgcn_mfma_f32_16x16x32_f16(af[m2][0], bf[n2][0], acc[m2][n2], 0, 0, 0);
        acc[m2][n2] = __builtin_amdgcn_mfma_f32_16x16x32_f16(af[m2][1], bf[n2][1], acc[m2][n2], 0, 0, 0);
      }
    __builtin_amdgcn_s_setprio(0);
    asm volatile("" ::: "memory");
    __builtin_amdgcn_s_barrier();
    asm volatile("" ::: "memory");
    buf = nbuf;
  }
}

// ---------------------------------------------------------------------------
// Merged Q/K/V projection: C[m,n] = sum_k Xh[m,k]*Wt[n,k] + bias, N=3072.
// ---------------------------------------------------------------------------
__global__ __launch_bounds__(512, 2)
void proj_qkv(const f16* __restrict__ Xh, const f16* __restrict__ Wt,
              const float* __restrict__ bq, const float* __restrict__ bk,
              const float* __restrict__ bv,
              f16* __restrict__ Qh, f16* __restrict__ Kh, f16* __restrict__ Vt) {
  const int jtn = blockIdx.x, itm = blockIdx.y;
  const int arow0 = itm * 256, col0 = jtn * 256;
  __shared__ f16 SA[2][256 * 64];
  __shared__ f16 SB[2][256 * 64];
  const int tid = threadIdx.x, lane = tid & 63, wv = tid >> 6;
  f32x4 acc[8][4] = {};
  kloop256(Xh + (size_t)arow0 * KSZ, KSZ, Wt + (size_t)col0 * KSZ, KSZ,
           KSZ / 64, SA, SB, acc, wv, lane);

  const int wr = wv >> 2, wc = wv & 3, fr = lane & 15, quad = lane >> 4;
  const int mat = jtn >> 2;                 // 0=Q, 1=K, 2=V
  const float* bp = (mat == 0) ? bq : (mat == 1) ? bk : bv;
  const int cb = col0 - mat * 1024 + wc * 64;
#pragma unroll
  for (int mi = 0; mi < 8; ++mi) {
#pragma unroll
    for (int ni = 0; ni < 4; ++ni) {
      const int cl = cb + ni * 16 + fr;
      const float bc = bp[cl];
      const int grow = arow0 + wr * 128 + mi * 16 + quad * 4;
      f32x4 v = acc[mi][ni];
      if (mat == 2) {
        const int bb = grow >> 11, t0 = grow & 2047;
        f16x4 pk;
#pragma unroll
        for (int rg = 0; rg < 4; ++rg) pk[rg] = (f16)(v[rg] + bc);
        *(f16x4*)&Vt[((size_t)bb * D_ + cl) * T_ + t0] = pk;
      } else {
        f16* O = (mat == 0) ? Qh : Kh;
#pragma unroll
        for (int rg = 0; rg < 4; ++rg)
          O[(size_t)(grow + rg) * KSZ + cl] = (f16)(v[rg] + bc);
      }
    }
  }
}

// ---------------------------------------------------------------------------
// Fused triangular QK pass (256x256 tiles): S = Q.K^T, per-tile column stats
// (m, sum-exp) -> pm/pd, and E = exp(S - m_tile_j) -> Ec (0 above diagonal).
// ---------------------------------------------------------------------------
__global__ __launch_bounds__(512, 2)
void qk_fused(const f16* __restrict__ Q, const f16* __restrict__ Km,
              float* __restrict__ pm, float* __restrict__ pd,
              f16* __restrict__ Ec) {
  const int p = blockIdx.x, b = blockIdx.y;
  int itg = (int)((sqrtf(8.f * p + 1.f) - 1.f) * 0.5f);
  while ((itg + 1) * (itg + 2) / 2 <= p) ++itg;
  while (itg * (itg + 1) / 2 > p) --itg;
  const int jt = p - itg * (itg + 1) / 2;
  const bool diag = (jt == itg);
  const int arow0 = itg * 256, col0 = jt * 256;

  __shared__ f16 SA[2][256 * 64];
  __shared__ f16 SB[2][256 * 64];
  __shared__ float red_m[8][64];
  __shared__ float red_d[8][64];
  __shared__ float mb[256];

  const int tid = threadIdx.x, lane = tid & 63, wv = tid >> 6;
  f32x4 acc[8][4] = {};
  kloop256(Q + (size_t)b * T_ * KSZ + (size_t)arow0 * KSZ, KSZ,
           Km + (size_t)b * T_ * KSZ + (size_t)col0 * KSZ, KSZ,
           KSZ / 64, SA, SB, acc, wv, lane);

  const int wr = wv >> 2, wc = wv & 3, fr = lane & 15, quad = lane >> 4;
  // per-column (m, d) over this block's 256 rows: two-pass max then exp.
#pragma unroll
  for (int ni = 0; ni < 4; ++ni) {
    const int cl = wc * 64 + ni * 16 + fr;
    const int gj = col0 + cl;
    float lm = -INFINITY;
#pragma unroll
    for (int mi = 0; mi < 8; ++mi) {
      const int gi0 = arow0 + wr * 128 + mi * 16 + quad * 4;
#pragma unroll
      for (int rg = 0; rg < 4; ++rg)
        if (!diag || (gi0 + rg >= gj)) lm = fmaxf(lm, acc[mi][ni][rg]);
    }
    float ld = 0.f;
#pragma unroll
    for (int mi = 0; mi < 8; ++mi) {
      const int gi0 = arow0 + wr * 128 + mi * 16 + quad * 4;
#pragma unroll
      for (int rg = 0; rg < 4; ++rg)
        if (!diag || (gi0 + rg >= gj)) ld += __expf(acc[mi][ni][rg] - lm);
    }
    sm_combine(lm, ld, __shfl_xor(lm, 16), __shfl_xor(ld, 16));
    sm_combine(lm, ld, __shfl_xor(lm, 32), __shfl_xor(ld, 32));
    if (quad == 0) { red_m[wv][ni * 16 + fr] = lm; red_d[wv][ni * 16 + fr] = ld; }
  }
  __syncthreads();
  if (tid < 256) {
    const int c = tid, wcc = c >> 6, cc = c & 63;
    float m1 = red_m[wcc][cc], d1 = red_d[wcc][cc];
    sm_combine(m1, d1, red_m[4 + wcc][cc], red_d[4 + wcc][cc]);
    const int idx = (itg * B_ + b) * T_ + col0 + c;
    pm[idx] = m1;
    pd[idx] = d1;
    mb[c] = m1;
  }
  __syncthreads();

  // store E = exp(S - m_tile_j) fp16 (0 above the diagonal)
  f16* Eb = Ec + (size_t)b * T_ * T_;
#pragma unroll
  for (int ni = 0; ni < 4; ++ni) {
    const int cl = wc * 64 + ni * 16 + fr;
    const int gj = col0 + cl;
    const float mj = mb[cl];
#pragma unroll
    for (int mi = 0; mi < 8; ++mi) {
      const int gi0 = arow0 + wr * 128 + mi * 16 + quad * 4;
#pragma unroll
      for (int rg = 0; rg < 4; ++rg) {
        float v = 0.f;
        if (!diag || (gi0 + rg >= gj)) v = __expf(acc[mi][ni][rg] - mj);
        Eb[(size_t)(gi0 + rg) * T_ + gj] = (f16)v;
      }
    }
  }
}

// ---------------------------------------------------------------------------
// PV + residual: out[b,t,v] = sum_j P[t,j] Vt[v,j] + X.
// 256-row x 128-col tiles, row-pairing (7-p, p): every block runs exactly
// 9*4 K-tiles -> 256 perfectly uniform blocks (1/CU).
// (vmcnt in part 2 also counts part-1 epilogue stores: conservative-safe,
//  vmcnt retires oldest-first so tile-t cp16s are always retired.)
// ---------------------------------------------------------------------------
__global__ __launch_bounds__(512, 2)
void pv_gemm(const f16* __restrict__ Pm, const f16* __restrict__ Vt,
             float* __restrict__ Of, const float* __restrict__ Resid) {
  const int jtc = blockIdx.x;            // 0..7 (128-col tile)
  const int prp = blockIdx.y;            // 0..3 (row pair)
  const int b = blockIdx.z;
  __shared__ f16 SA[2][256 * 64];
  __shared__ f16 SB[2][128 * 64];
  const int tid = threadIdx.x, lane = tid & 63, wv = tid >> 6;
  const int wr = wv >> 1, wc = wv & 1, fr = lane & 15, quad = lane >> 4;
  const int col0 = jtc * 128;
  const f16* Bg = Vt + (size_t)b * D_ * T_ + (size_t)col0 * T_;

#pragma unroll
  for (int part = 0; part < 2; ++part) {
    const int r = part ? prp : 7 - prp;
    const int arow0 = r * 256;
    f32x4 acc[4][4] = {};
    kloop_pv(Pm + (size_t)b * T_ * T_ + (size_t)arow0 * T_, T_, Bg, T_,
             (r + 1) * 4, SA, SB, acc, wv, lane);
#pragma unroll
    for (int mi = 0; mi < 4; ++mi) {
#pragma unroll
      for (int ni = 0; ni < 4; ++ni) {
        const int col = col0 + wc * 64 + ni * 16 + fr;
        const int grow = arow0 + wr * 64 + mi * 16 + quad * 4;
        f32x4 v = acc[mi][ni];
#pragma unroll
        for (int rg = 0; rg < 4; ++rg) {
          const size_t o = ((size_t)b * T_ + grow + rg) * D_ + col;
          Of[o] = v[rg] + Resid[o];
        }
      }
    }
  }
}

// ---------------------------------------------------------------------------
// Combine NSLOT partials per column; fold 1/sqrt(K)=1/32 into rcol.
// ---------------------------------------------------------------------------
__global__ __launch_bounds__(256)
void colstats_combine(const float* __restrict__ pm, const float* __restrict__ pd,
                      float* __restrict__ mcol, float* __restrict__ rcol) {
  const int j = blockIdx.x * 256 + threadIdx.x;
  const int b = blockIdx.y;
  float m = -INFINITY, d = 0.f;
  for (int s = 0; s < NSLOT; ++s) {
    const int idx = (s * B_ + b) * T_ + j;
    const float pmv = pm[idx], pdv = pd[idx];
    if (pdv > 0.f) sm_combine(m, d, pmv, pdv);
  }
  mcol[b * T_ + j] = m;
  rcol[b * T_ + j] = 1.f / (d * 32.f);
}

// ---------------------------------------------------------------------------
// Elementwise normalize (in place): P = E * exp(pm_tile - m_col) * r_col.
// 128x128 tiles over the lower triangle; pm slot = 256-row granule.
// ---------------------------------------------------------------------------
__global__ __launch_bounds__(256)
void pnorm_kernel(f16* __restrict__ Pc, const float* __restrict__ pm,
                  const float* __restrict__ mcol, const float* __restrict__ rcol) {
  const int p = blockIdx.x, b = blockIdx.y;
  int itg = (int)((sqrtf(8.f * p + 1.f) - 1.f) * 0.5f);
  while ((itg + 1) * (itg + 2) / 2 <= p) ++itg;
  while (itg * (itg + 1) / 2 > p) --itg;
  const int jt = p - itg * (itg + 1) / 2;

  __shared__ float f[128];
  const int tid = threadIdx.x;
  if (tid < 128) {
    const int gj = jt * 128 + tid;
    f[tid] = __expf(pm[((itg >> 1) * B_ + b) * T_ + gj] - mcol[b * T_ + gj]) * rcol[b * T_ + gj];
  }
  __syncthreads();

  f16* Pb = Pc + (size_t)b * T_ * T_ + (size_t)(itg * 128) * T_ + jt * 128;
  const int jl = (tid & 15) * 8, r0 = tid >> 4;
#pragma unroll
  for (int rr = 0; rr < 128; rr += 16) {
    f16x8 v = *(const f16x8*)&Pb[(size_t)(rr + r0) * T_ + jl];
    f16x8 o;
#pragma unroll
    for (int u = 0; u < 8; ++u) o[u] = (f16)((float)v[u] * f[jl + u]);
    *(f16x8*)&Pb[(size_t)(rr + r0) * T_ + jl] = o;
  }
}

// ---------------------------------------------------------------------------
extern "C" void kernel_launch(void* const* d_in, const int* in_sizes, int n_in,
                              void* d_out, int out_size, void* d_ws, size_t ws_size,
                              hipStream_t stream) {
  const float* X  = (const float*)d_in[0];
  const float* Wq = (const float*)d_in[1];
  const float* bq = (const float*)d_in[2];
  const float* Wk = (const float*)d_in[3];
  const float* bk = (const float*)d_in[4];
  const float* Wv = (const float*)d_in[5];
  const float* bv = (const float*)d_in[6];
  float* out = (float*)d_out;

  // Workspace carve (~200 MB)
  char* p = (char*)d_ws;
  auto carve = [&](size_t bytes) { char* r = p; p += (bytes + 255) & ~(size_t)255; return r; };
  f16*   Xh    = (f16*)carve((size_t)B_ * T_ * D_ * 2);
  f16*   Wqkvt = (f16*)carve((size_t)3 * D_ * KSZ * 2);
  f16*   Qh    = (f16*)carve((size_t)B_ * T_ * KSZ * 2);
  f16*   Kh    = (f16*)carve((size_t)B_ * T_ * KSZ * 2);
  f16*   Vt    = (f16*)carve((size_t)B_ * D_ * T_ * 2);
  f16*   Pc    = (f16*)carve((size_t)B_ * T_ * T_ * 2);   // E, then P in place
  float* pm    = (float*)carve((size_t)NSLOT * B_ * T_ * 4);
  float* pd    = (float*)carve((size_t)NSLOT * B_ * T_ * 4);
  float* mcol  = (float*)carve((size_t)B_ * T_ * 4);
  float* rcol  = (float*)carve((size_t)B_ * T_ * 4);

  const dim3 blk(256);

  // Prep: cast + weight transposes into concatenated [3072][1024] f16.
  hipMemsetAsync(pd, 0, (size_t)NSLOT * B_ * T_ * 4, stream);
  cast_f16_kernel<<<dim3((B_ * T_ * D_ / 4) / 256), blk, 0, stream>>>(X, Xh);
  transcast_kernel<<<dim3(32, 32), blk, 0, stream>>>(Wq, Wqkvt);
  transcast_kernel<<<dim3(32, 32), blk, 0, stream>>>(Wk, Wqkvt + (size_t)D_ * KSZ);
  transcast_kernel<<<dim3(32, 32), blk, 0, stream>>>(Wv, Wqkvt + (size_t)2 * D_ * KSZ);

  // Merged QKV projection (MFMA, 256^2 core, 2-barrier counted-vmcnt loop)
  proj_qkv<<<dim3(12, 64), dim3(512), 0, stream>>>(Xh, Wqkvt, bq, bk, bv, Qh, Kh, Vt);

  // Fused QK pass: stats + E = exp(S - m_tile) into Pc
  qk_fused<<<dim3(NTRI256, B_), dim3(512), 0, stream>>>(Qh, Kh, pm, pd, Pc);
  colstats_combine<<<dim3(T_ / 256, B_), blk, 0, stream>>>(pm, pd, mcol, rcol);

  // Elementwise rescale E -> P (in place)
  pnorm_kernel<<<dim3(NTRI128, B_), blk, 0, stream>>>(Pc, pm, mcol, rcol);

  // PV + residual: paired row-tiles, uniform 256 blocks
  pv_gemm<<<dim3(8, 4, 8), dim3(512), 0, stream>>>(Pc, Vt, out, X);
}